// Round 11
// baseline (533.957 us; speedup 1.0000x reference)
//
#include <hip/hip_runtime.h>
#include <hip/hip_bf16.h>

#define NT_ 10000
#define B_  128
#define S_  500

typedef _Float16 h2_t __attribute__((ext_vector_type(2)));
typedef unsigned int uint32;

__device__ __forceinline__ uint32 pack2(float a, float b) {
    return __builtin_bit_cast(uint32, __builtin_amdgcn_cvt_pkrtz(a, b));
}
__device__ __forceinline__ float dot2(uint32 w, uint32 h, float acc) {
#if __has_builtin(__builtin_amdgcn_fdot2)
    return __builtin_amdgcn_fdot2(__builtin_bit_cast(h2_t, w),
                                  __builtin_bit_cast(h2_t, h), acc, false);
#else
    h2_t wv = __builtin_bit_cast(h2_t, w), hv = __builtin_bit_cast(h2_t, h);
    acc = fmaf((float)wv[0], (float)hv[0], acc);
    return fmaf((float)wv[1], (float)hv[1], acc);
#endif
}
__device__ __forceinline__ float rcpf(float x) {
    return __builtin_amdgcn_rcpf(x);
}
// quad_perm DPP add-reduce: x += x[lane^1]; x += x[lane^2]  (VALU pipe, no DS)
__device__ __forceinline__ float qstep(float x, const int ctrl) {
    int p;
    if (ctrl == 0xB1)
        p = __builtin_amdgcn_update_dpp(0, __builtin_bit_cast(int, x), 0xB1, 0xF, 0xF, true);
    else
        p = __builtin_amdgcn_update_dpp(0, __builtin_bit_cast(int, x), 0x4E, 0xF, 0xF, true);
    return x + __builtin_bit_cast(float, p);
}
#define QUAD_SUM(x) do { x = qstep(x, 0xB1); x = qstep(x, 0x4E); } while (0)

// ---------------------------------------------------------------------------
// Kernel A: per-topic precompute (blockIdx.y = 0: topicAct, 1: topicGate)
// ---------------------------------------------------------------------------
__global__ __launch_bounds__(128) void prep_topic(
    const float* __restrict__ emb_topic,
    const float* __restrict__ emb_resps,
    const float* __restrict__ W_in,
    const float* __restrict__ W_gate,
    float* __restrict__ topicAct,
    float* __restrict__ topicGate,
    float* __restrict__ respAct)
{
    const int u    = threadIdx.x;
    const int blk  = blockIdx.x;
    const int mode = blockIdx.y;
    __shared__ float e[8][128];

    if (blk == NT_ / 8) {
        if (mode) return;
        e[0][u] = emb_resps[u];
        e[1][u] = emb_resps[128 + u];
        __syncthreads();
        float a0 = 0.f, a1 = 0.f;
        for (int k = 0; k < 128; ++k) {
            float wv = W_in[(128 + k) * 128 + u];
            a0 += e[0][k] * wv;
            a1 += e[1][k] * wv;
        }
        respAct[u]       = a0;
        respAct[128 + u] = a1;
        return;
    }

    const int t0 = blk * 8;
    #pragma unroll
    for (int j = 0; j < 8; ++j) e[j][u] = emb_topic[(t0 + j) * 128 + u];
    __syncthreads();

    const float* __restrict__ W = mode ? (W_gate + 256 * 128) : W_in;
    float acc[8];
    #pragma unroll
    for (int j = 0; j < 8; ++j) acc[j] = 0.f;
    for (int k = 0; k < 128; ++k) {
        float wv = W[k * 128 + u];
        #pragma unroll
        for (int j = 0; j < 8; ++j) acc[j] += e[j][k] * wv;
    }
    float* __restrict__ dst = mode ? topicGate : topicAct;
    #pragma unroll
    for (int j = 0; j < 8; ++j) dst[(t0 + j) * 128 + u] = acc[j];
}

// ---------------------------------------------------------------------------
// Kernel B: per-(topic,resp) streams (blockIdx.y = mat 0..3)
// ---------------------------------------------------------------------------
__global__ __launch_bounds__(128) void prep_streams(
    const float* __restrict__ topicAct,
    const float* __restrict__ topicGate,
    const float* __restrict__ respAct,
    const float* __restrict__ b_in,
    const float* __restrict__ W_time,
    const float* __restrict__ W_att,
    const float* __restrict__ W_hint,
    const float* __restrict__ W_gate,
    float* __restrict__ streams)
{
    const int u   = threadIdx.x;
    const int t0  = blockIdx.x * 8;
    const int mat = blockIdx.y;
    __shared__ float a_lds[16][128];

    const float bi = b_in[u];
    const float r0 = respAct[u];
    const float r1 = respAct[128 + u];
    #pragma unroll
    for (int j = 0; j < 8; ++j) {
        float ta = topicAct[(t0 + j) * 128 + u];
        a_lds[j * 2 + 0][u] = fmaxf(ta + r0 + bi, 0.f);
        a_lds[j * 2 + 1][u] = fmaxf(ta + r1 + bi, 0.f);
    }
    __syncthreads();

    const float* __restrict__ Wp =
        (mat == 0 ? W_time + 128 : mat == 1 ? W_att + 128 :
         mat == 2 ? W_hint + 128 : W_gate + 128 * 128) + u;

    float acc[16];
    #pragma unroll
    for (int r = 0; r < 16; ++r) acc[r] = 0.f;
    for (int k = 0; k < 128; ++k) {
        float wv = Wp[(size_t)k * 128];
        #pragma unroll
        for (int r = 0; r < 16; ++r) acc[r] += a_lds[r][k] * wv;
    }
    #pragma unroll
    for (int r = 0; r < 16; ++r) {
        float v = acc[r];
        int   t = t0 + (r >> 1);
        if (mat == 3) v += topicGate[t * 128 + u];
        streams[((size_t)t * 2 + (r & 1)) * 512 + mat * 128 + u] = v;
    }
}

// ---------------------------------------------------------------------------
// Kernel C: 500-step recurrence. 1 block/row, 512 thr = 128 u x 4 k-quads.
// R11 vs R10 (445us): ht-FORWARDING. The recurrence is linear in H:
//   ht(s+1) = w(s+1)·H(s+1) = gme(s)*[w(s+1)·H(s)] + [w(s+1)·w(s)]*lge(s)
// so b1 = w(s+1)·H(s) and cs = w(s+1)·w(s) are computed during step s's
// (ds_read-latency-dominated) dot phase, and ht(s+1) = fma(gme,b1,cs*lge)
// right after the epilogue. The whole top-of-step hp phase vanishes from
// the serial chain; the H update falls off the critical path entirely
// (needed only ~200cyc later by step s+1's b1). ONE barrier at END of step.
// ---------------------------------------------------------------------------
#define LDS_BARRIER()                                         \
    do {                                                      \
        asm volatile("s_waitcnt lgkmcnt(0)" ::: "memory");    \
        __builtin_amdgcn_s_barrier();                         \
        asm volatile("" ::: "memory");                        \
    } while (0)

__global__ __launch_bounds__(512) __attribute__((amdgpu_waves_per_eu(2, 2)))
void recurrent(
    const int*   __restrict__ topics, const int* __restrict__ resps,
    const float* __restrict__ tf_, const float* __restrict__ af_,
    const float* __restrict__ hf_, const int* __restrict__ masks,
    const float* __restrict__ q_matrix, const float* __restrict__ init_h,
    const float* __restrict__ W_out,  const float* __restrict__ b_out,
    const float* __restrict__ W_time, const float* __restrict__ b_time,
    const float* __restrict__ W_att,  const float* __restrict__ b_att,
    const float* __restrict__ W_hint, const float* __restrict__ b_hint,
    const float* __restrict__ W_cap,  const float* __restrict__ b_cap,
    const float* __restrict__ w_lg,
    const float* __restrict__ W_gate, const float* __restrict__ b_gate,
    const float* __restrict__ streams,
    float* __restrict__ out)
{
    const int tid  = threadIdx.x;
    const int u    = tid >> 2;      // 0..127
    const int q    = tid & 3;       // k-quad / role
    const int lane = tid & 63;
    const int wv   = tid >> 6;      // wave 0..7
    const int b    = blockIdx.x;

    __shared__ int    sb_lds[S_];             // (topic*2+resp)*512
    __shared__ int    qb_lds[S_];             // topic*32
    __shared__ float4 sc_lds[S_];             // {tf, af, hf, capm(sign=mask)}
    __shared__ float  w_lds[2][32];
    __shared__ __align__(16) _Float16 ht16[2][176];  // quads at q*40 (bank-spread)
    __shared__ float  outbuf[8][2][128];      // [slot][which][u]

    const int base = b * S_;

    // ---- preload per-step data; fold cap+mask into sc.w ----
    {
        const float wcv0 = W_cap[0], wcv1 = W_cap[1], wcv2 = W_cap[2],
                    wcv3 = W_cap[3], wcv4 = W_cap[4], wcv5 = W_cap[5],
                    wcv6 = W_cap[6], wcv7 = W_cap[7], bcv = b_cap[0];
        for (int i = tid; i < S_; i += 512) {
            const int tpc = topics[base + i];
            const int rsp = resps [base + i];
            sb_lds[i] = (tpc * 2 + rsp) * 512;
            qb_lds[i] = tpc * 32;
            const float tf = tf_[base + i], af = af_[base + i], hf = hf_[base + i];
            const float capin = wcv0*tf + wcv1*af + wcv2*hf + wcv3*(tf*af)
                              + wcv4*(tf*hf) + wcv5*(af*hf) + wcv6*(tf*af*hf)
                              + wcv7 + bcv;
            const float cap = rcpf(1.f + __expf(-capin));
            sc_lds[i] = make_float4(tf, af, hf, masks[base + i] ? cap : -cap);
        }
    }

    // ---- f16-packed weights: ALL 5 mats for this lane's k-quad (80 u32) ----
    uint32 Wo[16], Wt[16], Wa[16], Wh[16], Wg[16];
    const int kb = q * 32;
    #pragma unroll
    for (int i = 0; i < 16; ++i) {
        const int k0 = kb + 2 * i, k1 = k0 + 1;
        Wo[i] = pack2(W_out [k0 * 128 + u],         W_out [k1 * 128 + u]);
        Wt[i] = pack2(W_time[(129 + k0) * 128 + u], W_time[(129 + k1) * 128 + u]);
        Wa[i] = pack2(W_att [(129 + k0) * 128 + u], W_att [(129 + k1) * 128 + u]);
        Wh[i] = pack2(W_hint[(129 + k0) * 128 + u], W_hint[(129 + k1) * 128 + u]);
        Wg[i] = pack2(W_gate[k0 * 128 + u],         W_gate[k1 * 128 + u]);
    }
    #pragma unroll
    for (int i = 0; i < 16; ++i) {
        asm volatile("" : "+v"(Wo[i]), "+v"(Wt[i]), "+v"(Wa[i]),
                          "+v"(Wh[i]), "+v"(Wg[i]));
    }

    // H[m][u] for m = q*8 .. q*8+7
    float H[8];
    #pragma unroll
    for (int j = 0; j < 8; ++j) H[j] = init_h[(q * 8 + j) * 128 + u];

    // per-lane role constants (q0: out/sigmoid, q1: time, q2: att, q3: hint)
    const float cst_b  = (q == 0 ? b_out : q == 1 ? b_time :
                          q == 2 ? b_att : b_hint)[u];
    const float cst_w0 = q == 1 ? W_time[u] : q == 2 ? W_att[u] :
                         q == 3 ? W_hint[u] : 0.f;
    const float wl_own = q == 1 ? w_lg[0] : q == 2 ? w_lg[1] :
                         q == 3 ? w_lg[2] : 0.f;
    const float bg = b_gate[u];
    const float aa = q == 0 ? 1.f : 2.f;    // sigmoid vs tanh exponent scale
    const float bb = q == 0 ? 1.f : 2.f;    // sigmoid vs tanh numerator
    // sv gather role: lane q gathers stream of mat q (time,att,hint,gate)
    const int   svofs = q * 128 + u;
    const float selt = (q == 0) ? 1.f : 0.f;
    const float sela = (q == 1) ? 1.f : 0.f;
    const float selh = (q == 2) ? 1.f : 0.f;
    const float selg = (q == 3) ? 1.f : 0.f;

    float* out_imp = out + B_ * (S_ - 1);

    __syncthreads();   // preload visible

    // ---- prime: sv j = stream val for step j; qq j = w row for step j+2 ----
    float sv0 = streams[sb_lds[0] + svofs];
    float sv1 = streams[sb_lds[1] + svofs];
    float sv2 = streams[sb_lds[2] + svofs];
    float sv3 = streams[sb_lds[3] + svofs];
    float qq0 = 0.f, qq1 = 0.f, qq2 = 0.f, qq3 = 0.f;
    if (tid < 32) {
        w_lds[0][tid] = q_matrix[qb_lds[0] + tid];   // w row 0
        w_lds[1][tid] = q_matrix[qb_lds[1] + tid];   // w row 1
        qq0 = q_matrix[qb_lds[2] + tid];             // row 2 (written step 0)
        qq1 = q_matrix[qb_lds[3] + tid];             // row 3 (written step 1)
        qq2 = q_matrix[qb_lds[4] + tid];             // row 4 (written step 2)
        qq3 = q_matrix[qb_lds[5] + tid];             // row 5 (written step 3)
    }
    __syncthreads();
    float4 wA = *(const float4*)&w_lds[0][q * 8];
    float4 wB = *(const float4*)&w_lds[0][q * 8 + 4];

    // ---- prologue: ht(0) via the direct path ----
    {
        float hp = wA.x * H[0] + wA.y * H[1] + wA.z * H[2] + wA.w * H[3]
                 + wB.x * H[4] + wB.y * H[5] + wB.z * H[6] + wB.w * H[7];
        QUAD_SUM(hp);
        if (q == 0) ht16[0][(u >> 5) * 40 + (u & 31)] = (_Float16)hp;
    }
    LDS_BARRIER();

// One step body. J = phase (0..3). ht16[J&1] holds ht(s) (written end of s-1
// or prologue). w(s) in wA/wB; w(s+1) read from w_lds[(s+1)&1] at top.
// SV = stream val for s (reloaded for s+4); QQ = w row for s+2 (written to
// w_lds[s&1] this step, reloaded for s+6). Barrier at END of body.
#define STEP(J, SV, QQ)                                                        \
    {                                                                          \
        const int s = s4 + (J);                                                \
        const float4 wAn = *(const float4*)&w_lds[((J) & 1) ^ 1][q * 8];       \
        const float4 wBn = *(const float4*)&w_lds[((J) & 1) ^ 1][q * 8 + 4];   \
        const float4 sc = sc_lds[s];                                           \
        const float tf = sc.x, af = sc.y, hf = sc.z;                           \
        const float cap = fabsf(sc.w);                                         \
        const float msk = sc.w > 0.f ? 1.f : 0.f;                              \
        /* 5 dots over own k-quad of ht(s) */                                  \
        const _Float16* htq = &ht16[(J) & 1][q * 40];                          \
        float zoA = 0, ztA = 0, zaA = 0, zhA = 0, zgA = 0;                     \
        float zoB = 0, ztB = 0, zaB = 0, zhB = 0, zgB = 0;                     \
        _Pragma("unroll")                                                      \
        for (int c = 0; c < 4; ++c) {                                          \
            const uint4 h4 = *(const uint4*)(htq + c * 8);                     \
            zoA = dot2(Wo[c*4+0], h4.x, zoA); zoA = dot2(Wo[c*4+1], h4.y, zoA);\
            zoB = dot2(Wo[c*4+2], h4.z, zoB); zoB = dot2(Wo[c*4+3], h4.w, zoB);\
            ztA = dot2(Wt[c*4+0], h4.x, ztA); ztA = dot2(Wt[c*4+1], h4.y, ztA);\
            ztB = dot2(Wt[c*4+2], h4.z, ztB); ztB = dot2(Wt[c*4+3], h4.w, ztB);\
            zaA = dot2(Wa[c*4+0], h4.x, zaA); zaA = dot2(Wa[c*4+1], h4.y, zaA);\
            zaB = dot2(Wa[c*4+2], h4.z, zaB); zaB = dot2(Wa[c*4+3], h4.w, zaB);\
            zhA = dot2(Wh[c*4+0], h4.x, zhA); zhA = dot2(Wh[c*4+1], h4.y, zhA);\
            zhB = dot2(Wh[c*4+2], h4.z, zhB); zhB = dot2(Wh[c*4+3], h4.w, zhB);\
            zgA = dot2(Wg[c*4+0], h4.x, zgA); zgA = dot2(Wg[c*4+1], h4.y, zgA);\
            zgB = dot2(Wg[c*4+2], h4.z, zgB); zgB = dot2(Wg[c*4+3], h4.w, zgB);\
        }                                                                      \
        /* b1 = w(s+1)·H(s) partial; cs = w(s+1)·w(s) partial */               \
        float b1 = wAn.x * H[0] + wAn.y * H[1] + wAn.z * H[2] + wAn.w * H[3]   \
                 + wBn.x * H[4] + wBn.y * H[5] + wBn.z * H[6] + wBn.w * H[7];  \
        float cs = wAn.x * wA.x + wAn.y * wA.y + wAn.z * wA.z + wAn.w * wA.w   \
                 + wBn.x * wB.x + wBn.y * wB.y + wBn.z * wB.z + wBn.w * wB.w;  \
        float zo = zoA + zoB;                                                  \
        float zt = fmaf(selt, SV, ztA + ztB);                                  \
        float za = fmaf(sela, SV, zaA + zaB);                                  \
        float zh = fmaf(selh, SV, zhA + zhB);                                  \
        float zg = fmaf(selg, SV, zgA + zgB);                                  \
        {                                                                      \
            const int sp4 = (s + 4 < S_) ? s + 4 : S_ - 1;                     \
            SV = streams[sb_lds[sp4] + svofs];  /* for s+4, same phase next */ \
        }                                                                      \
        QUAD_SUM(zo); QUAD_SUM(zt); QUAD_SUM(za); QUAD_SUM(zh); QUAD_SUM(zg);  \
        QUAD_SUM(b1); QUAD_SUM(cs);                                            \
        /* epilogue: unified sigmoid/tanh */                                   \
        const float zsel = q == 0 ? zo : q == 1 ? zt : q == 2 ? za : zh;       \
        const float fac  = q == 1 ? tf : q == 2 ? af : q == 3 ? hf : 0.f;      \
        const float arg  = zsel + fac * cst_w0 + cst_b;                        \
        const float e1   = __expf(aa * arg);                                   \
        const float val  = fmaf(-bb, rcpf(e1 + 1.f), 1.f);                     \
        float gs = wl_own * fac * val;                                         \
        QUAD_SUM(gs);                                                          \
        const float lg    = cap * fmaxf(gs, 0.f);                              \
        const float gamma = rcpf(1.f + __expf(-(zg + bg)));                    \
        const float gme = 1.f + msk * (gamma - 1.f);                           \
        const float lge = msk * lg;                                            \
        /* ht(s+1) by linearity; write for next step */                        \
        const float htn = fmaf(gme, b1, cs * lge);                             \
        if (q == 0) {                                                          \
            ht16[((J) & 1) ^ 1][(u >> 5) * 40 + (u & 31)] = (_Float16)htn;     \
            outbuf[s & 7][0][u] = msk * val;                                   \
            outbuf[s & 7][1][u] = lge;                                         \
        }                                                                      \
        /* H update: off the critical chain (needed only by s+1's b1) */       \
        H[0] = fmaf(gme, H[0], wA.x * lge); H[1] = fmaf(gme, H[1], wA.y * lge);\
        H[2] = fmaf(gme, H[2], wA.z * lge); H[3] = fmaf(gme, H[3], wA.w * lge);\
        H[4] = fmaf(gme, H[4], wB.x * lge); H[5] = fmaf(gme, H[5], wB.y * lge);\
        H[6] = fmaf(gme, H[6], wB.z * lge); H[7] = fmaf(gme, H[7], wB.w * lge);\
        if (tid < 32) {                                                        \
            w_lds[(J) & 1][tid] = QQ;           /* w row for s+2 */            \
            const int sp6 = (s + 6 < S_) ? s + 6 : S_ - 1;                     \
            QQ = q_matrix[qb_lds[sp6] + tid];   /* row s+6, same phase next */ \
        }                                                                      \
        if ((J) == 0 && s4 > 0) {  /* flush steps s4-4..s4-1 */                \
            const int st = (s4 - 4) + (wv >> 1);                               \
            const int which = wv & 1;                                          \
            const float2 p = *(const float2*)&outbuf[st & 7][which][2 * lane]; \
            float v = p.x + p.y;                                               \
            _Pragma("unroll")                                                  \
            for (int o = 1; o < 64; o <<= 1) v += __shfl_xor(v, o);            \
            if (lane == 0) {                                                   \
                v *= (1.f / 128.f);                                            \
                if (which == 0) { if (st >= 1) out[b * (S_ - 1) + st - 1] = v; } \
                else            out_imp[b * S_ + st] = v;                      \
            }                                                                  \
        }                                                                      \
        LDS_BARRIER();                                                         \
        wA = wAn; wB = wBn;                                                    \
    }

    #pragma unroll 1
    for (int s4 = 0; s4 < S_; s4 += 4) {
        STEP(0, sv0, qq0)
        STEP(1, sv1, qq1)
        STEP(2, sv2, qq2)
        STEP(3, sv3, qq3)
    }
#undef STEP

    // ---- final flush: steps 496..499 ----
    __syncthreads();
    {
        const int st = 496 + (wv >> 1);
        const int which = wv & 1;
        const float2 p = *(const float2*)&outbuf[st & 7][which][2 * lane];
        float v = p.x + p.y;
        #pragma unroll
        for (int o = 1; o < 64; o <<= 1) v += __shfl_xor(v, o);
        if (lane == 0) {
            v *= (1.f / 128.f);
            if (which == 0) out[b * (S_ - 1) + st - 1] = v;
            else            out_imp[b * S_ + st] = v;
        }
    }
}

// ---------------------------------------------------------------------------
extern "C" void kernel_launch(void* const* d_in, const int* in_sizes, int n_in,
                              void* d_out, int out_size, void* d_ws, size_t ws_size,
                              hipStream_t stream)
{
    (void)in_sizes; (void)n_in; (void)out_size; (void)ws_size;

    const int*   topics    = (const int*)  d_in[0];
    const int*   resps     = (const int*)  d_in[1];
    const float* tf        = (const float*)d_in[2];
    const float* af        = (const float*)d_in[3];
    const float* hf        = (const float*)d_in[4];
    const int*   masks     = (const int*)  d_in[5];
    /* d_in[6] = training (ignored) */
    const float* emb_topic = (const float*)d_in[7];
    const float* emb_resps = (const float*)d_in[8];
    const float* q_matrix  = (const float*)d_in[9];
    const float* W_in      = (const float*)d_in[10];
    const float* b_in      = (const float*)d_in[11];
    const float* init_h    = (const float*)d_in[12];
    const float* W_out     = (const float*)d_in[13];
    const float* b_out     = (const float*)d_in[14];
    const float* W_time    = (const float*)d_in[15];
    const float* b_time    = (const float*)d_in[16];
    const float* W_att     = (const float*)d_in[17];
    const float* b_att     = (const float*)d_in[18];
    const float* W_hint    = (const float*)d_in[19];
    const float* b_hint    = (const float*)d_in[20];
    const float* W_cap     = (const float*)d_in[21];
    const float* b_cap     = (const float*)d_in[22];
    const float* w_lg      = (const float*)d_in[23];
    const float* W_gate    = (const float*)d_in[24];
    const float* b_gate    = (const float*)d_in[25];

    float* ws        = (float*)d_ws;
    float* topicAct  = ws;                         // 10000*128
    float* topicGate = topicAct + NT_ * 128;       // 10000*128
    float* respAct   = topicGate + NT_ * 128;      // 256
    float* streams   = respAct + 256;              // 10000*2*512

    prep_topic  <<<dim3(NT_ / 8 + 1, 2), 128, 0, stream>>>(
        emb_topic, emb_resps, W_in, W_gate, topicAct, topicGate, respAct);
    prep_streams<<<dim3(NT_ / 8, 4),     128, 0, stream>>>(
        topicAct, topicGate, respAct, b_in,
        W_time, W_att, W_hint, W_gate, streams);
    recurrent   <<<B_, 512, 0, stream>>>(topics, resps, tf, af, hf, masks,
                                         q_matrix, init_h,
                                         W_out, b_out, W_time, b_time,
                                         W_att, b_att, W_hint, b_hint,
                                         W_cap, b_cap, w_lg, W_gate, b_gate,
                                         streams, (float*)d_out);
}

// Round 13
// 476.106 us; speedup vs baseline: 1.1215x; 1.1215x over previous
//
#include <hip/hip_runtime.h>
#include <hip/hip_bf16.h>

#define NT_ 10000
#define B_  128
#define S_  500

typedef _Float16 h2_t __attribute__((ext_vector_type(2)));
typedef unsigned int uint32;

__device__ __forceinline__ uint32 pack2(float a, float b) {
    return __builtin_bit_cast(uint32, __builtin_amdgcn_cvt_pkrtz(a, b));
}
__device__ __forceinline__ float dot2(uint32 w, uint32 h, float acc) {
#if __has_builtin(__builtin_amdgcn_fdot2)
    return __builtin_amdgcn_fdot2(__builtin_bit_cast(h2_t, w),
                                  __builtin_bit_cast(h2_t, h), acc, false);
#else
    h2_t wv = __builtin_bit_cast(h2_t, w), hv = __builtin_bit_cast(h2_t, h);
    acc = fmaf((float)wv[0], (float)hv[0], acc);
    return fmaf((float)wv[1], (float)hv[1], acc);
#endif
}
__device__ __forceinline__ float rcpf(float x) {
    return __builtin_amdgcn_rcpf(x);
}
// DPP add-reduce stage with compile-time control (update_dpp requires an
// integer-constant ctrl -> template parameter).
template <int CTRL>
__device__ __forceinline__ float dppAdd(float x) {
    int p = __builtin_amdgcn_update_dpp(0, __builtin_bit_cast(int, x),
                                        CTRL, 0xF, 0xF, true);
    return x + __builtin_bit_cast(float, p);
}
#define QUAD_SUM(x) do { x = dppAdd<0xB1>(x); x = dppAdd<0x4E>(x); } while (0)

// Full-wave64 sum on the VALU pipe (classic GCN DPP ladder), replacing the
// 6x chained ds_permute shfl reduction (~240 DS-pipe cyc -> ~24 VALU cyc).
__device__ __forceinline__ float waveSum64(float v) {
    v = dppAdd<0x111>(v);   // row_shr:1
    v = dppAdd<0x112>(v);   // row_shr:2
    v = dppAdd<0x114>(v);   // row_shr:4
    v = dppAdd<0x118>(v);   // row_shr:8
    v = dppAdd<0x142>(v);   // row_bcast:15
    v = dppAdd<0x143>(v);   // row_bcast:31
    return __builtin_bit_cast(float,
        __builtin_amdgcn_readlane(__builtin_bit_cast(int, v), 63));
}

// ---------------------------------------------------------------------------
// Kernel A: per-topic precompute (blockIdx.y = 0: topicAct, 1: topicGate)
// ---------------------------------------------------------------------------
__global__ __launch_bounds__(128) void prep_topic(
    const float* __restrict__ emb_topic,
    const float* __restrict__ emb_resps,
    const float* __restrict__ W_in,
    const float* __restrict__ W_gate,
    float* __restrict__ topicAct,
    float* __restrict__ topicGate,
    float* __restrict__ respAct)
{
    const int u    = threadIdx.x;
    const int blk  = blockIdx.x;
    const int mode = blockIdx.y;
    __shared__ float e[8][128];

    if (blk == NT_ / 8) {
        if (mode) return;
        e[0][u] = emb_resps[u];
        e[1][u] = emb_resps[128 + u];
        __syncthreads();
        float a0 = 0.f, a1 = 0.f;
        for (int k = 0; k < 128; ++k) {
            float wv = W_in[(128 + k) * 128 + u];
            a0 += e[0][k] * wv;
            a1 += e[1][k] * wv;
        }
        respAct[u]       = a0;
        respAct[128 + u] = a1;
        return;
    }

    const int t0 = blk * 8;
    #pragma unroll
    for (int j = 0; j < 8; ++j) e[j][u] = emb_topic[(t0 + j) * 128 + u];
    __syncthreads();

    const float* __restrict__ W = mode ? (W_gate + 256 * 128) : W_in;
    float acc[8];
    #pragma unroll
    for (int j = 0; j < 8; ++j) acc[j] = 0.f;
    for (int k = 0; k < 128; ++k) {
        float wv = W[k * 128 + u];
        #pragma unroll
        for (int j = 0; j < 8; ++j) acc[j] += e[j][k] * wv;
    }
    float* __restrict__ dst = mode ? topicGate : topicAct;
    #pragma unroll
    for (int j = 0; j < 8; ++j) dst[(t0 + j) * 128 + u] = acc[j];
}

// ---------------------------------------------------------------------------
// Kernel B: per-(topic,resp) streams (blockIdx.y = mat 0..3)
// ---------------------------------------------------------------------------
__global__ __launch_bounds__(128) void prep_streams(
    const float* __restrict__ topicAct,
    const float* __restrict__ topicGate,
    const float* __restrict__ respAct,
    const float* __restrict__ b_in,
    const float* __restrict__ W_time,
    const float* __restrict__ W_att,
    const float* __restrict__ W_hint,
    const float* __restrict__ W_gate,
    float* __restrict__ streams)
{
    const int u   = threadIdx.x;
    const int t0  = blockIdx.x * 8;
    const int mat = blockIdx.y;
    __shared__ float a_lds[16][128];

    const float bi = b_in[u];
    const float r0 = respAct[u];
    const float r1 = respAct[128 + u];
    #pragma unroll
    for (int j = 0; j < 8; ++j) {
        float ta = topicAct[(t0 + j) * 128 + u];
        a_lds[j * 2 + 0][u] = fmaxf(ta + r0 + bi, 0.f);
        a_lds[j * 2 + 1][u] = fmaxf(ta + r1 + bi, 0.f);
    }
    __syncthreads();

    const float* __restrict__ Wp =
        (mat == 0 ? W_time + 128 : mat == 1 ? W_att + 128 :
         mat == 2 ? W_hint + 128 : W_gate + 128 * 128) + u;

    float acc[16];
    #pragma unroll
    for (int r = 0; r < 16; ++r) acc[r] = 0.f;
    for (int k = 0; k < 128; ++k) {
        float wv = Wp[(size_t)k * 128];
        #pragma unroll
        for (int r = 0; r < 16; ++r) acc[r] += a_lds[r][k] * wv;
    }
    #pragma unroll
    for (int r = 0; r < 16; ++r) {
        float v = acc[r];
        int   t = t0 + (r >> 1);
        if (mat == 3) v += topicGate[t * 128 + u];
        streams[((size_t)t * 2 + (r & 1)) * 512 + mat * 128 + u] = v;
    }
}

// ---------------------------------------------------------------------------
// Kernel C: 500-step recurrence. 1 block/row, 512 thr = 128 u x 4 k-quads.
// R13 = R10 (445us proven best) + flush converted from 6x chained
// ds_permute shfl to a DPP VALU ladder, hoisted right after the barrier so
// it runs under the dot-phase ds_read shadow. (R12 failed to compile: DPP
// ctrl must be a constant -> template param.)
// ---------------------------------------------------------------------------
#define LDS_BARRIER()                                         \
    do {                                                      \
        asm volatile("s_waitcnt lgkmcnt(0)" ::: "memory");    \
        __builtin_amdgcn_s_barrier();                         \
        asm volatile("" ::: "memory");                        \
    } while (0)

__global__ __launch_bounds__(512) __attribute__((amdgpu_waves_per_eu(2, 2)))
void recurrent(
    const int*   __restrict__ topics, const int* __restrict__ resps,
    const float* __restrict__ tf_, const float* __restrict__ af_,
    const float* __restrict__ hf_, const int* __restrict__ masks,
    const float* __restrict__ q_matrix, const float* __restrict__ init_h,
    const float* __restrict__ W_out,  const float* __restrict__ b_out,
    const float* __restrict__ W_time, const float* __restrict__ b_time,
    const float* __restrict__ W_att,  const float* __restrict__ b_att,
    const float* __restrict__ W_hint, const float* __restrict__ b_hint,
    const float* __restrict__ W_cap,  const float* __restrict__ b_cap,
    const float* __restrict__ w_lg,
    const float* __restrict__ W_gate, const float* __restrict__ b_gate,
    const float* __restrict__ streams,
    float* __restrict__ out)
{
    const int tid  = threadIdx.x;
    const int u    = tid >> 2;      // 0..127
    const int q    = tid & 3;       // k-quad / role
    const int lane = tid & 63;
    const int wv   = tid >> 6;      // wave 0..7
    const int b    = blockIdx.x;

    __shared__ int    sb_lds[S_];             // (topic*2+resp)*512
    __shared__ int    qb_lds[S_];             // topic*32
    __shared__ float4 sc_lds[S_];             // {tf, af, hf, capm(sign=mask)}
    __shared__ float  w_lds[2][32];
    __shared__ __align__(16) _Float16 ht16[2][176];  // quads at q*40 (bank-spread)
    __shared__ float  outbuf[8][2][128];      // [slot][which][u]

    const int base = b * S_;

    // ---- preload per-step data; fold cap+mask into sc.w ----
    {
        const float wcv0 = W_cap[0], wcv1 = W_cap[1], wcv2 = W_cap[2],
                    wcv3 = W_cap[3], wcv4 = W_cap[4], wcv5 = W_cap[5],
                    wcv6 = W_cap[6], wcv7 = W_cap[7], bcv = b_cap[0];
        for (int i = tid; i < S_; i += 512) {
            const int tpc = topics[base + i];
            const int rsp = resps [base + i];
            sb_lds[i] = (tpc * 2 + rsp) * 512;
            qb_lds[i] = tpc * 32;
            const float tf = tf_[base + i], af = af_[base + i], hf = hf_[base + i];
            const float capin = wcv0*tf + wcv1*af + wcv2*hf + wcv3*(tf*af)
                              + wcv4*(tf*hf) + wcv5*(af*hf) + wcv6*(tf*af*hf)
                              + wcv7 + bcv;
            const float cap = rcpf(1.f + __expf(-capin));
            sc_lds[i] = make_float4(tf, af, hf, masks[base + i] ? cap : -cap);
        }
    }

    // ---- f16-packed weights: ALL 5 mats for this lane's k-quad (80 u32) ----
    uint32 Wo[16], Wt[16], Wa[16], Wh[16], Wg[16];
    const int kb = q * 32;
    #pragma unroll
    for (int i = 0; i < 16; ++i) {
        const int k0 = kb + 2 * i, k1 = k0 + 1;
        Wo[i] = pack2(W_out [k0 * 128 + u],         W_out [k1 * 128 + u]);
        Wt[i] = pack2(W_time[(129 + k0) * 128 + u], W_time[(129 + k1) * 128 + u]);
        Wa[i] = pack2(W_att [(129 + k0) * 128 + u], W_att [(129 + k1) * 128 + u]);
        Wh[i] = pack2(W_hint[(129 + k0) * 128 + u], W_hint[(129 + k1) * 128 + u]);
        Wg[i] = pack2(W_gate[k0 * 128 + u],         W_gate[k1 * 128 + u]);
    }
    #pragma unroll
    for (int i = 0; i < 16; ++i) {
        asm volatile("" : "+v"(Wo[i]), "+v"(Wt[i]), "+v"(Wa[i]),
                          "+v"(Wh[i]), "+v"(Wg[i]));
    }

    // H[m][u] for m = q*8 .. q*8+7
    float H[8];
    #pragma unroll
    for (int j = 0; j < 8; ++j) H[j] = init_h[(q * 8 + j) * 128 + u];

    // per-lane role constants (q0: out/sigmoid, q1: time, q2: att, q3: hint)
    const float cst_b  = (q == 0 ? b_out : q == 1 ? b_time :
                          q == 2 ? b_att : b_hint)[u];
    const float cst_w0 = q == 1 ? W_time[u] : q == 2 ? W_att[u] :
                         q == 3 ? W_hint[u] : 0.f;
    const float wl_own = q == 1 ? w_lg[0] : q == 2 ? w_lg[1] :
                         q == 3 ? w_lg[2] : 0.f;
    const float bg = b_gate[u];
    const float aa = q == 0 ? 1.f : 2.f;    // sigmoid vs tanh exponent scale
    const float bb = q == 0 ? 1.f : 2.f;    // sigmoid vs tanh numerator
    // sv gather role: lane q gathers stream of mat q (time,att,hint,gate)
    const int   svofs = q * 128 + u;
    const float selt = (q == 0) ? 1.f : 0.f;
    const float sela = (q == 1) ? 1.f : 0.f;
    const float selh = (q == 2) ? 1.f : 0.f;
    const float selg = (q == 3) ? 1.f : 0.f;

    float* out_imp = out + B_ * (S_ - 1);

    __syncthreads();   // preload visible

    // ---- prime: sv j = stream val for step j; qq j = q row for step j+1 ----
    float sv0 = streams[sb_lds[0] + svofs];
    float sv1 = streams[sb_lds[1] + svofs];
    float sv2 = streams[sb_lds[2] + svofs];
    float sv3 = streams[sb_lds[3] + svofs];
    float qq0 = 0.f, qq1 = 0.f, qq2 = 0.f, qq3 = 0.f;
    if (tid < 32) {
        w_lds[0][tid] = q_matrix[qb_lds[0] + tid];
        qq0 = q_matrix[qb_lds[1] + tid];
        qq1 = q_matrix[qb_lds[2] + tid];
        qq2 = q_matrix[qb_lds[3] + tid];
        qq3 = q_matrix[qb_lds[4] + tid];
    }
    __syncthreads();
    float4 wA = *(const float4*)&w_lds[0][q * 8];
    float4 wB = *(const float4*)&w_lds[0][q * 8 + 4];

// One step body. J = compile-time phase (0..3); SV holds this step's stream
// value and is reloaded for step s+4 (consumed at the same phase next iter);
// QQ holds the q_matrix row for step s+1 and is reloaded for step s+5.
#define STEP(J, SV, QQ)                                                        \
    {                                                                          \
        const int s = s4 + (J);                                                \
        const float4 sc = sc_lds[s];                                           \
        const float tf = sc.x, af = sc.y, hf = sc.z;                           \
        const float cap = fabsf(sc.w);                                         \
        const float msk = sc.w > 0.f ? 1.f : 0.f;                              \
        /* h_tilde partial + DPP quad reduce */                                \
        float hp = wA.x * H[0] + wA.y * H[1] + wA.z * H[2] + wA.w * H[3]       \
                 + wB.x * H[4] + wB.y * H[5] + wB.z * H[6] + wB.w * H[7];      \
        QUAD_SUM(hp);                                                          \
        if (q == 0) ht16[(J) & 1][(u >> 5) * 40 + (u & 31)] = (_Float16)hp;    \
        if (tid < 32) {                                                        \
            w_lds[((J) & 1) ^ 1][tid] = QQ;                                    \
            const int sp5 = (s + 5 < S_) ? s + 5 : S_ - 1;                     \
            QQ = q_matrix[qb_lds[sp5] + tid];  /* row for s+5, used J next */  \
        }                                                                      \
        LDS_BARRIER();                                                         \
        /* deferred flush (DPP ladder, runs under the dot ds_read shadow) */   \
        if ((J) == 0 && s4 > 0) {                                              \
            const int st = (s4 - 4) + (wv >> 1);                               \
            const int which = wv & 1;                                          \
            const float2 p = *(const float2*)&outbuf[st & 7][which][2 * lane]; \
            const float v = waveSum64(p.x + p.y) * (1.f / 128.f);              \
            if (lane == 0) {                                                   \
                if (which == 0) { if (st >= 1) out[b * (S_ - 1) + st - 1] = v; } \
                else            out_imp[b * S_ + st] = v;                      \
            }                                                                  \
        }                                                                      \
        const float4 wAn = *(const float4*)&w_lds[((J) & 1) ^ 1][q * 8];       \
        const float4 wBn = *(const float4*)&w_lds[((J) & 1) ^ 1][q * 8 + 4];   \
        /* 5 dots over own k-quad */                                           \
        const _Float16* htq = &ht16[(J) & 1][q * 40];                          \
        float zoA = 0, ztA = 0, zaA = 0, zhA = 0, zgA = 0;                     \
        float zoB = 0, ztB = 0, zaB = 0, zhB = 0, zgB = 0;                     \
        _Pragma("unroll")                                                      \
        for (int c = 0; c < 4; ++c) {                                          \
            const uint4 h4 = *(const uint4*)(htq + c * 8);                     \
            zoA = dot2(Wo[c*4+0], h4.x, zoA); zoA = dot2(Wo[c*4+1], h4.y, zoA);\
            zoB = dot2(Wo[c*4+2], h4.z, zoB); zoB = dot2(Wo[c*4+3], h4.w, zoB);\
            ztA = dot2(Wt[c*4+0], h4.x, ztA); ztA = dot2(Wt[c*4+1], h4.y, ztA);\
            ztB = dot2(Wt[c*4+2], h4.z, ztB); ztB = dot2(Wt[c*4+3], h4.w, ztB);\
            zaA = dot2(Wa[c*4+0], h4.x, zaA); zaA = dot2(Wa[c*4+1], h4.y, zaA);\
            zaB = dot2(Wa[c*4+2], h4.z, zaB); zaB = dot2(Wa[c*4+3], h4.w, zaB);\
            zhA = dot2(Wh[c*4+0], h4.x, zhA); zhA = dot2(Wh[c*4+1], h4.y, zhA);\
            zhB = dot2(Wh[c*4+2], h4.z, zhB); zhB = dot2(Wh[c*4+3], h4.w, zhB);\
            zgA = dot2(Wg[c*4+0], h4.x, zgA); zgA = dot2(Wg[c*4+1], h4.y, zgA);\
            zgB = dot2(Wg[c*4+2], h4.z, zgB); zgB = dot2(Wg[c*4+3], h4.w, zgB);\
        }                                                                      \
        float zo = zoA + zoB;                                                  \
        float zt = fmaf(selt, SV, ztA + ztB);                                  \
        float za = fmaf(sela, SV, zaA + zaB);                                  \
        float zh = fmaf(selh, SV, zhA + zhB);                                  \
        float zg = fmaf(selg, SV, zgA + zgB);                                  \
        {                                                                      \
            const int sp4 = (s + 4 < S_) ? s + 4 : S_ - 1;                     \
            SV = streams[sb_lds[sp4] + svofs];  /* for s+4, same phase next */ \
        }                                                                      \
        QUAD_SUM(zo); QUAD_SUM(zt); QUAD_SUM(za); QUAD_SUM(zh); QUAD_SUM(zg);  \
        /* epilogue: unified sigmoid/tanh */                                   \
        const float zsel = q == 0 ? zo : q == 1 ? zt : q == 2 ? za : zh;       \
        const float fac  = q == 1 ? tf : q == 2 ? af : q == 3 ? hf : 0.f;      \
        const float arg  = zsel + fac * cst_w0 + cst_b;                        \
        const float e1   = __expf(aa * arg);                                   \
        const float val  = fmaf(-bb, rcpf(e1 + 1.f), 1.f);                     \
        float gs = wl_own * fac * val;                                         \
        QUAD_SUM(gs);                                                          \
        const float lg    = cap * fmaxf(gs, 0.f);                              \
        const float gamma = rcpf(1.f + __expf(-(zg + bg)));                    \
        const float gme = 1.f + msk * (gamma - 1.f);                           \
        const float lge = msk * lg;                                            \
        H[0] = fmaf(gme, H[0], wA.x * lge); H[1] = fmaf(gme, H[1], wA.y * lge);\
        H[2] = fmaf(gme, H[2], wA.z * lge); H[3] = fmaf(gme, H[3], wA.w * lge);\
        H[4] = fmaf(gme, H[4], wB.x * lge); H[5] = fmaf(gme, H[5], wB.y * lge);\
        H[6] = fmaf(gme, H[6], wB.z * lge); H[7] = fmaf(gme, H[7], wB.w * lge);\
        if (q == 0) {                                                          \
            outbuf[s & 7][0][u] = msk * val;                                   \
            outbuf[s & 7][1][u] = lge;                                         \
        }                                                                      \
        wA = wAn; wB = wBn;                                                    \
    }

    #pragma unroll 1
    for (int s4 = 0; s4 < S_; s4 += 4) {
        STEP(0, sv0, qq0)
        STEP(1, sv1, qq1)
        STEP(2, sv2, qq2)
        STEP(3, sv3, qq3)
    }
#undef STEP

    // ---- final flush: steps 496..499 ----
    __syncthreads();
    {
        const int st = 496 + (wv >> 1);
        const int which = wv & 1;
        const float2 p = *(const float2*)&outbuf[st & 7][which][2 * lane];
        const float v = waveSum64(p.x + p.y) * (1.f / 128.f);
        if (lane == 0) {
            if (which == 0) out[b * (S_ - 1) + st - 1] = v;
            else            out_imp[b * S_ + st] = v;
        }
    }
}

// ---------------------------------------------------------------------------
extern "C" void kernel_launch(void* const* d_in, const int* in_sizes, int n_in,
                              void* d_out, int out_size, void* d_ws, size_t ws_size,
                              hipStream_t stream)
{
    (void)in_sizes; (void)n_in; (void)out_size; (void)ws_size;

    const int*   topics    = (const int*)  d_in[0];
    const int*   resps     = (const int*)  d_in[1];
    const float* tf        = (const float*)d_in[2];
    const float* af        = (const float*)d_in[3];
    const float* hf        = (const float*)d_in[4];
    const int*   masks     = (const int*)  d_in[5];
    /* d_in[6] = training (ignored) */
    const float* emb_topic = (const float*)d_in[7];
    const float* emb_resps = (const float*)d_in[8];
    const float* q_matrix  = (const float*)d_in[9];
    const float* W_in      = (const float*)d_in[10];
    const float* b_in      = (const float*)d_in[11];
    const float* init_h    = (const float*)d_in[12];
    const float* W_out     = (const float*)d_in[13];
    const float* b_out     = (const float*)d_in[14];
    const float* W_time    = (const float*)d_in[15];
    const float* b_time    = (const float*)d_in[16];
    const float* W_att     = (const float*)d_in[17];
    const float* b_att     = (const float*)d_in[18];
    const float* W_hint    = (const float*)d_in[19];
    const float* b_hint    = (const float*)d_in[20];
    const float* W_cap     = (const float*)d_in[21];
    const float* b_cap     = (const float*)d_in[22];
    const float* w_lg      = (const float*)d_in[23];
    const float* W_gate    = (const float*)d_in[24];
    const float* b_gate    = (const float*)d_in[25];

    float* ws        = (float*)d_ws;
    float* topicAct  = ws;                         // 10000*128
    float* topicGate = topicAct + NT_ * 128;       // 10000*128
    float* respAct   = topicGate + NT_ * 128;      // 256
    float* streams   = respAct + 256;              // 10000*2*512

    prep_topic  <<<dim3(NT_ / 8 + 1, 2), 128, 0, stream>>>(
        emb_topic, emb_resps, W_in, W_gate, topicAct, topicGate, respAct);
    prep_streams<<<dim3(NT_ / 8, 4),     128, 0, stream>>>(
        topicAct, topicGate, respAct, b_in,
        W_time, W_att, W_hint, W_gate, streams);
    recurrent   <<<B_, 512, 0, stream>>>(topics, resps, tf, af, hf, masks,
                                         q_matrix, init_h,
                                         W_out, b_out, W_time, b_time,
                                         W_att, b_att, W_hint, b_hint,
                                         W_cap, b_cap, w_lg, W_gate, b_gate,
                                         streams, (float*)d_out);
}